// Round 9
// baseline (422.354 us; speedup 1.0000x reference)
//
#include <hip/hip_runtime.h>
#include <math.h>

// Model8 R9: temporally-clustered edge scatter. R8 top-5 = k_a2 (~56us,
// WRITE 67-81MB vs 12.8MB ideal): 4B scattered writes -> repeated 64B
// write-allocate RMW on the same lines. Now chunk-per-block LDS staging:
// hist -> block scan -> bucket-segmented LDS -> slot-ordered emission
// (consecutive lanes hit consecutive addresses). pos[] deleted (A2 rebuilds
// slots locally). transform layer-1 fused into A2's dispatch; k_b is pure
// bucket CSR build.

#define PAD 12    // padded row stride for fp32 [N,10] arrays (48B)
#define LP 8      // XLb packed row stride in u32 (32B)
#define MAXB 784  // LDS bucket array size (>= (N+127)/128)
#define CHK 4096  // edges per chunk

__device__ __forceinline__ float lrelu02(float v) { return v > 0.f ? v : 0.2f * v; }

__device__ __forceinline__ unsigned pk_bf16(float a, float b)
{
    unsigned ua = __float_as_uint(a), ub = __float_as_uint(b);
    ua += 0x7fffu + ((ua >> 16) & 1u);
    ub += 0x7fffu + ((ub >> 16) & 1u);
    return (ua >> 16) | (ub & 0xffff0000u);
}
__device__ __forceinline__ float bf_lo(unsigned u) { return __uint_as_float(u << 16); }
__device__ __forceinline__ float bf_hi(unsigned u) { return __uint_as_float(u & 0xffff0000u); }

// Streaming transform body: accumulators only, uniform weight reads.
template <int NS>
__device__ __forceinline__ void transform_body(
    int n, const float* __restrict__ s0, const float* __restrict__ s1,
    const float* __restrict__ s2, const float* __restrict__ x1,
    const float* __restrict__ Wl, const float* __restrict__ Wr,
    unsigned* __restrict__ XLb, float* __restrict__ XR)
{
    float al[10], ar[10];
#pragma unroll
    for (int g = 0; g < 10; ++g) { al[g] = 0.f; ar[g] = 0.f; }
    int o = 0;
#define TB_BLOCK(SP)                                                        \
    {                                                                       \
        const float4* pr = (const float4*)((SP) + n * PAD);                 \
        float4 v0 = pr[0], v1 = pr[1], v2 = pr[2];                          \
        float fv[10] = {v0.x, v0.y, v0.z, v0.w, v1.x, v1.y, v1.z, v1.w,     \
                        v2.x, v2.y};                                        \
        _Pragma("unroll") for (int k = 0; k < 10; ++k)                      \
        {                                                                   \
            _Pragma("unroll") for (int g = 0; g < 10; ++g)                  \
            {                                                               \
                al[g] += fv[k] * Wl[(o + k) * 10 + g];                      \
                ar[g] += fv[k] * Wr[(o + k) * 10 + g];                      \
            }                                                               \
        }                                                                   \
        o += 10;                                                            \
    }
    if constexpr (NS >= 1) TB_BLOCK(s0)
    if constexpr (NS >= 2) TB_BLOCK(s1)
    if constexpr (NS >= 3) TB_BLOCK(s2)
#undef TB_BLOCK
#pragma unroll
    for (int k = 0; k < 15; ++k) {
        float fv = x1[n * 15 + k];
#pragma unroll
        for (int g = 0; g < 10; ++g) {
            al[g] += fv * Wl[(o + k) * 10 + g];
            ar[g] += fv * Wr[(o + k) * 10 + g];
        }
    }
    uint4 q0;
    q0.x = pk_bf16(al[0], al[1]);
    q0.y = pk_bf16(al[2], al[3]);
    q0.z = pk_bf16(al[4], al[5]);
    q0.w = pk_bf16(al[6], al[7]);
    uint4 q1;
    q1.x = pk_bf16(al[8], al[9]);
    q1.y = 0; q1.z = 0; q1.w = 0;
    uint4* pb = (uint4*)(XLb + (size_t)n * LP);
    pb[0] = q0;
    pb[1] = q1;
    float4* po = (float4*)(XR + n * PAD);
    po[0] = make_float4(ar[0], ar[1], ar[2], ar[3]);
    po[1] = make_float4(ar[4], ar[5], ar[6], ar[7]);
    po[2] = make_float4(ar[8], ar[9], 0.f, 0.f);
}

// Fused: blocks [0,PA) -> A1 (LDS hist -> cntg column); [PA,..) -> x_ init.
__global__ __launch_bounds__(256) void k_a1_init(
    const int* __restrict__ edst, int E, int* __restrict__ cntg, int PA,
    const float* __restrict__ x1, const float* __restrict__ W,
    const float* __restrict__ b, float* __restrict__ xo, int N, int NBK)
{
    if ((int)blockIdx.x < PA) {
        __shared__ int h[MAXB];
        for (int j = threadIdx.x; j < NBK; j += 256) h[j] = 0;
        __syncthreads();
        int base = blockIdx.x * CHK;
        for (int k = 0; k < CHK / 256; ++k) {
            int i = base + k * 256 + threadIdx.x;
            if (i < E) atomicAdd(&h[edst[i] >> 7], 1);
        }
        __syncthreads();
        for (int j = threadIdx.x; j < NBK; j += 256)
            cntg[(size_t)j * PA + blockIdx.x] = h[j];
    } else {
        int n = ((int)blockIdx.x - PA) * 256 + (int)threadIdx.x;
        if (n >= N) return;
        float acc[10];
#pragma unroll
        for (int g = 0; g < 10; ++g) acc[g] = b[g];
#pragma unroll
        for (int k = 0; k < 15; ++k) {
            float fv = x1[n * 15 + k];
#pragma unroll
            for (int g = 0; g < 10; ++g) acc[g] += fv * W[k * 10 + g];
        }
        float4* po = (float4*)(xo + n * PAD);
        po[0] = make_float4(fmaxf(acc[0], 0.f), fmaxf(acc[1], 0.f),
                            fmaxf(acc[2], 0.f), fmaxf(acc[3], 0.f));
        po[1] = make_float4(fmaxf(acc[4], 0.f), fmaxf(acc[5], 0.f),
                            fmaxf(acc[6], 0.f), fmaxf(acc[7], 0.f));
        po[2] = make_float4(fmaxf(acc[8], 0.f), fmaxf(acc[9], 0.f), 0.f, 0.f);
    }
}

// Scan stage A.
__global__ __launch_bounds__(1024) void k_scanA(
    const int* __restrict__ cntg, int* __restrict__ bases,
    int* __restrict__ bsumA, int TOT)
{
    __shared__ int wsum[16];
    int t = threadIdx.x;
    int i = blockIdx.x * 1024 + t;
    int lane = t & 63, w = t >> 6;
    int x = (i < TOT) ? cntg[i] : 0;
    int incl = x;
#pragma unroll
    for (int off = 1; off < 64; off <<= 1) {
        int u = __shfl_up(incl, off);
        if (lane >= off) incl += u;
    }
    if (lane == 63) wsum[w] = incl;
    __syncthreads();
    int woff = 0;
    for (int k = 0; k < w; ++k) woff += wsum[k];
    incl += woff;
    if (i < TOT) bases[i] = incl - x;
    if (t == 1023) bsumA[blockIdx.x] = incl;
}

// Scan stage B (single 1024-thread block, NBLKA <= 1024) + zero vsums +
// rowptr[N] = Etot.
__global__ __launch_bounds__(1024) void k_scanB(
    const int* __restrict__ bsumA, int* __restrict__ boffA, int NBLKA,
    float* __restrict__ vsums, int* __restrict__ rowptr, int N, int Etot)
{
    __shared__ int wsum[16];
    int t = threadIdx.x;
    int lane = t & 63, w = t >> 6;
    int x = (t < NBLKA) ? bsumA[t] : 0;
    int incl = x;
#pragma unroll
    for (int off = 1; off < 64; off <<= 1) {
        int u = __shfl_up(incl, off);
        if (lane >= off) incl += u;
    }
    if (lane == 63) wsum[w] = incl;
    __syncthreads();
    int woff = 0;
    for (int k = 0; k < w; ++k) woff += wsum[k];
    incl += woff;
    if (t < NBLKA) boffA[t] = incl - x;
    if (t < 16) vsums[t] = 0.f;
    if (t == 0) rowptr[N] = Etot;
}

// Scan stage C.
__global__ __launch_bounds__(1024) void k_scanC(
    int* __restrict__ bases, const int* __restrict__ boffA, int TOT)
{
    int i = blockIdx.x * 1024 + threadIdx.x;
    if (i < TOT) bases[i] += boffA[blockIdx.x];
}

// Fused: blocks [0,PA) -> A2 clustered placement; [PA,..) -> transform layer1.
// A2 per chunk: p1 hist+slot record -> block scan -> p2 place into
// bucket-segmented LDS -> p3 slot-ordered global emission.
__global__ __launch_bounds__(256) void k_a2tr1(
    const int* __restrict__ esrc, const int* __restrict__ edst, int E,
    const int* __restrict__ bases, unsigned* __restrict__ pairs, int PA,
    const float* __restrict__ s0a, const float* __restrict__ x1,
    const float* __restrict__ Wl, const float* __restrict__ Wr,
    unsigned* __restrict__ XLb, float* __restrict__ XR, int N, int NBK)
{
    __shared__ int h[MAXB];                 // counts -> lstart (scanned)
    __shared__ unsigned tmp[CHK];           // edst | p<<17 per edge
    __shared__ unsigned vals[CHK];          // bucket-segmented packed edges
    __shared__ unsigned short bkt16[CHK];   // bucket per slot
    __shared__ int wtotS[4];
    if ((int)blockIdx.x < PA) {
        int t = threadIdx.x;
        for (int j = t; j < NBK; j += 256) h[j] = 0;
        __syncthreads();
        int base = blockIdx.x * CHK;
        int nE = E - base; nE = nE > CHK ? CHK : nE;
        // p1: hist + record (edst,p) per edge
        for (int k = 0; k < CHK / 256; ++k) {
            int e = k * 256 + t;
            if (e < nE) {
                unsigned dv = (unsigned)edst[base + e];
                int p = atomicAdd(&h[dv >> 7], 1);
                tmp[e] = dv | ((unsigned)p << 17);
            }
        }
        __syncthreads();
        // block exclusive scan of h[0..NBK) (4 buckets/thread)
        {
            int j = t * 4;
            int v0 = 0, v1 = 0, v2 = 0, v3 = 0;
            if (j < NBK) v0 = h[j];
            if (j + 1 < NBK) v1 = h[j + 1];
            if (j + 2 < NBK) v2 = h[j + 2];
            if (j + 3 < NBK) v3 = h[j + 3];
            int s = v0 + v1 + v2 + v3;
            int lane = t & 63, wv = t >> 6;
            int incl = s;
#pragma unroll
            for (int off = 1; off < 64; off <<= 1) {
                int u = __shfl_up(incl, off);
                if (lane >= off) incl += u;
            }
            if (lane == 63) wtotS[wv] = incl;
            __syncthreads();
            int woff = 0;
            for (int k2 = 0; k2 < wv; ++k2) woff += wtotS[k2];
            int ebase = incl - s + woff;
            __syncthreads();
            if (j < NBK) h[j] = ebase;
            if (j + 1 < NBK) h[j + 1] = ebase + v0;
            if (j + 2 < NBK) h[j + 2] = ebase + v0 + v1;
            if (j + 3 < NBK) h[j + 3] = ebase + v0 + v1 + v2;
        }
        __syncthreads();
        // p2: place into bucket-segmented LDS
        for (int k = 0; k < CHK / 256; ++k) {
            int e = k * 256 + t;
            if (e < nE) {
                unsigned w = tmp[e];
                unsigned dv = w & 0x1FFFFu;
                int p = (int)(w >> 17);
                int b = (int)(dv >> 7);
                int slot = h[b] + p;
                vals[slot] = (unsigned)esrc[base + e] | ((dv & 127u) << 17);
                bkt16[slot] = (unsigned short)b;
            }
        }
        __syncthreads();
        // p3: slot-ordered emission (consecutive lanes -> consecutive dests)
        for (int k = 0; k < CHK / 256; ++k) {
            int e = k * 256 + t;
            if (e < nE) {
                int b = (int)bkt16[e];
                int within = e - h[b];
                int dest = bases[(size_t)b * PA + blockIdx.x] + within;
                pairs[dest] = vals[e];
            }
        }
    } else {
        int n = ((int)blockIdx.x - PA) * 256 + (int)threadIdx.x;
        if (n >= N) return;
        transform_body<1>(n, s0a, nullptr, nullptr, x1, Wl, Wr, XLb, XR);
    }
}

// Per-bucket CSR build (self-loop slot 0).
__global__ __launch_bounds__(256) void k_b(
    const unsigned* __restrict__ pairs, const int* __restrict__ bases,
    int* __restrict__ rowptr, int* __restrict__ deg, int* __restrict__ sidx,
    int N, int NBK, int PA, int E)
{
    __shared__ int cnt[128];
    __shared__ int cur[128];
    __shared__ int wtot;
    int t = threadIdx.x;
    if (t < 128) cnt[t] = 0;
    __syncthreads();
    int b = blockIdx.x;
    int p0 = bases[(size_t)b * PA];
    int p1 = (b + 1 < NBK) ? bases[(size_t)(b + 1) * PA] : E;
    int n0 = b << 7;
    int nn = N - n0; nn = nn < 0 ? 0 : (nn > 128 ? 128 : nn);
    for (int i = p0 + t; i < p1; i += 256) atomicAdd(&cnt[pairs[i] >> 17], 1);
    __syncthreads();
    int x = 0, incl = 0;
    if (t < 128) {
        x = cnt[t] + (t < nn ? 1 : 0);
        incl = x;
        int lane = t & 63;
#pragma unroll
        for (int off = 1; off < 64; off <<= 1) {
            int u = __shfl_up(incl, off);
            if (lane >= off) incl += u;
        }
        if (t == 63) wtot = incl;
    }
    __syncthreads();
    int sb = p0 + (b << 7);
    if (t < 128) {
        if (t >= 64) incl += wtot;
        int st = incl - x;
        if (t < nn) {
            int r = sb + st;
            rowptr[n0 + t] = r;
            deg[n0 + t] = cnt[t] + 1;
            sidx[r] = n0 + t;        // self-loop slot 0
            cur[t] = st + 1;
        } else {
            cur[t] = st;
        }
    }
    __syncthreads();
    for (int i = p0 + t; i < p1; i += 256) {
        unsigned w = pairs[i];
        int l = w >> 17, s = w & 0x1FFFF;
        int off = atomicAdd(&cur[l], 1);
        sidx[sb + off] = s;
    }
}

// Transform (layers 2/3).
template <int NS>
__global__ __launch_bounds__(256) void k_transform(
    const float* __restrict__ s0, const float* __restrict__ s1,
    const float* __restrict__ s2, const float* __restrict__ x1,
    const float* __restrict__ Wl, const float* __restrict__ Wr,
    unsigned* __restrict__ XLb, float* __restrict__ XR, int N)
{
    int n = blockIdx.x * blockDim.x + threadIdx.x;
    if (n >= N) return;
    transform_body<NS>(n, s0, s1, s2, x1, Wl, Wr, XLb, XR);
}

// CSR gather + edge softmax + finalize. 16 lanes/node, batch-2 ILP.
__global__ __launch_bounds__(256) void k_gather(
    const int* __restrict__ rowptr, const int* __restrict__ deg,
    const int* __restrict__ sidx,
    const unsigned* __restrict__ XLb, const float* __restrict__ XR,
    const float* __restrict__ att, const float* __restrict__ b,
    float* __restrict__ xo, int N)
{
    int node = blockIdx.x * 16 + (threadIdx.x >> 4);
    int l16 = threadIdx.x & 15;
    float acc[10];
#pragma unroll
    for (int g = 0; g < 10; ++g) acc[g] = 0.f;
    float den = 0.f;
    float satt[10];
#pragma unroll
    for (int g = 0; g < 10; ++g) satt[g] = att[g];
    if (node < N) {
        const float4* pr = (const float4*)(XR + node * PAD);
        float4 r0 = pr[0], r1 = pr[1], r2 = pr[2];
        float xr[10] = {r0.x, r0.y, r0.z, r0.w, r1.x, r1.y, r1.z, r1.w, r2.x, r2.y};
        int start = rowptr[node];
        int dgr = deg[node];
        int j = l16;
        while (j + 16 < dgr) {
            int s0 = sidx[start + j];
            int s1 = sidx[start + j + 16];
            const unsigned* pl0 = XLb + (size_t)s0 * LP;
            const unsigned* pl1 = XLb + (size_t)s1 * LP;
            uint4 qa = *(const uint4*)pl0;
            unsigned qa4 = pl0[4];
            uint4 qb = *(const uint4*)pl1;
            unsigned qb4 = pl1[4];
            float xa[10] = {bf_lo(qa.x), bf_hi(qa.x), bf_lo(qa.y), bf_hi(qa.y),
                            bf_lo(qa.z), bf_hi(qa.z), bf_lo(qa.w), bf_hi(qa.w),
                            bf_lo(qa4), bf_hi(qa4)};
            float xb[10] = {bf_lo(qb.x), bf_hi(qb.x), bf_lo(qb.y), bf_hi(qb.y),
                            bf_lo(qb.z), bf_hi(qb.z), bf_lo(qb.w), bf_hi(qb.w),
                            bf_lo(qb4), bf_hi(qb4)};
            float ea = 0.f, eb = 0.f;
#pragma unroll
            for (int g = 0; g < 10; ++g) {
                ea += lrelu02(xa[g] + xr[g]) * satt[g];
                eb += lrelu02(xb[g] + xr[g]) * satt[g];
            }
            float exa = __expf(ea), exb = __expf(eb);
#pragma unroll
            for (int g = 0; g < 10; ++g) acc[g] += exa * xa[g] + exb * xb[g];
            den += exa + exb;
            j += 32;
        }
        if (j < dgr) {
            int s = sidx[start + j];
            const unsigned* pl = XLb + (size_t)s * LP;
            uint4 q = *(const uint4*)pl;
            unsigned q4 = pl[4];
            float xl[10] = {bf_lo(q.x), bf_hi(q.x), bf_lo(q.y), bf_hi(q.y),
                            bf_lo(q.z), bf_hi(q.z), bf_lo(q.w), bf_hi(q.w),
                            bf_lo(q4), bf_hi(q4)};
            float e = 0.f;
#pragma unroll
            for (int g = 0; g < 10; ++g) e += lrelu02(xl[g] + xr[g]) * satt[g];
            float ex = __expf(e);
#pragma unroll
            for (int g = 0; g < 10; ++g) acc[g] += ex * xl[g];
            den += ex;
        }
    }
#pragma unroll
    for (int off = 1; off < 16; off <<= 1) {
        den += __shfl_xor(den, off);
#pragma unroll
        for (int g = 0; g < 10; ++g) acc[g] += __shfl_xor(acc[g], off);
    }
    if (node < N && l16 == 0) {
        float inv = 1.f / den;
        float r[10];
#pragma unroll
        for (int g = 0; g < 10; ++g) r[g] = fmaxf(acc[g] * inv + b[g], 0.f);
        float4* po = (float4*)(xo + node * PAD);
        po[0] = make_float4(r[0], r[1], r[2], r[3]);
        po[1] = make_float4(r[4], r[5], r[6], r[7]);
        po[2] = make_float4(r[8], r[9], 0.f, 0.f);
    }
}

// Fused homogeneous scoring: attack orders / deploy orders / value head.
__global__ __launch_bounds__(256) void k_scores(
    const float* __restrict__ xc, const float* __restrict__ x1,
    const float* __restrict__ x2,
    const int* __restrict__ asrc, const int* __restrict__ adst,
    const float* __restrict__ aarm,
    const int* __restrict__ dtgt, const float* __restrict__ darm,
    const float* __restrict__ atW, const float* __restrict__ atb,
    const float* __restrict__ dtW, const float* __restrict__ dtb,
    const float* __restrict__ oaW, const float* __restrict__ oab,
    const float* __restrict__ ovW, const float* __restrict__ ovb,
    const float* __restrict__ vtW, const float* __restrict__ vtb,
    const float* __restrict__ vaW, const float* __restrict__ vab,
    const float* __restrict__ vvW, const float* __restrict__ vvb,
    float* __restrict__ vsums, float2* __restrict__ OS,
    int AB, int DB, int NB, int N, int M)
{
    if ((int)blockIdx.x < AB) {
        int i = blockIdx.x * 256 + threadIdx.x;
        if (i >= M * 32) return;
        int m = i >> 5, a = i & 31;
        int s = asrc[i], d = adst[i];
        float arm = aarm[i];
        float ord[20];
#pragma unroll
        for (int j = 0; j < 20; ++j) ord[j] = atb[j];
        {
            const float4* pc = (const float4*)(xc + s * PAD);
            float4 c0 = pc[0], c1 = pc[1], c2 = pc[2];
            float fv[10] = {c0.x, c0.y, c0.z, c0.w, c1.x, c1.y, c1.z, c1.w,
                            c2.x, c2.y};
#pragma unroll
            for (int k = 0; k < 10; ++k)
#pragma unroll
                for (int j = 0; j < 20; ++j) ord[j] += fv[k] * atW[k * 20 + j];
        }
        {
            const float4* pc = (const float4*)(xc + d * PAD);
            float4 c0 = pc[0], c1 = pc[1], c2 = pc[2];
            float fv[10] = {c0.x, c0.y, c0.z, c0.w, c1.x, c1.y, c1.z, c1.w,
                            c2.x, c2.y};
#pragma unroll
            for (int k = 0; k < 10; ++k)
#pragma unroll
                for (int j = 0; j < 20; ++j)
                    ord[j] += fv[k] * atW[(10 + k) * 20 + j];
        }
#pragma unroll
        for (int k = 0; k < 12; ++k) {
            float fv = x1[s * 15 + 3 + k];
#pragma unroll
            for (int j = 0; j < 20; ++j) ord[j] += fv * atW[(20 + k) * 20 + j];
        }
        float d3 = 0.f, d4 = 0.f;
#pragma unroll
        for (int k = 0; k < 14; ++k) {
            float fv = x1[d * 15 + 1 + k];
            if (k == 2) d3 = fv;
            if (k == 3) d4 = fv;
#pragma unroll
            for (int j = 0; j < 20; ++j) ord[j] += fv * atW[(32 + k) * 20 + j];
        }
        float extra = 0.6f * arm - 0.7f * (d3 + d4);
#pragma unroll
        for (int j = 0; j < 20; ++j)
            ord[j] += arm * atW[46 * 20 + j] + extra * atW[47 * 20 + j];
        float asc = oab[0], vsc = ovb[0];
#pragma unroll
        for (int j = 0; j < 20; ++j) {
            float oj = fmaxf(ord[j], 0.f);
            asc += oj * oaW[j];
            vsc += oj * ovW[j];
        }
        OS[(size_t)m * 48 + a] = make_float2(asc, vsc);
    } else if ((int)blockIdx.x < AB + DB) {
        int i = ((int)blockIdx.x - AB) * 256 + threadIdx.x;
        if (i >= M * 16) return;
        int m = i >> 4, dd = i & 15;
        int tg = dtgt[i];
        float arm = darm[i];
        float ord[20];
#pragma unroll
        for (int j = 0; j < 20; ++j) ord[j] = dtb[j];
        {
            const float4* pc = (const float4*)(xc + tg * PAD);
            float4 c0 = pc[0], c1 = pc[1], c2 = pc[2];
            float fv[10] = {c0.x, c0.y, c0.z, c0.w, c1.x, c1.y, c1.z, c1.w,
                            c2.x, c2.y};
#pragma unroll
            for (int k = 0; k < 10; ++k)
#pragma unroll
                for (int j = 0; j < 20; ++j) ord[j] += fv[k] * dtW[k * 20 + j];
        }
#pragma unroll
        for (int k = 0; k < 12; ++k) {
            float fv = x1[tg * 15 + 3 + k];
#pragma unroll
            for (int j = 0; j < 20; ++j) ord[j] += fv * dtW[(10 + k) * 20 + j];
        }
#pragma unroll
        for (int j = 0; j < 20; ++j) ord[j] += arm * dtW[22 * 20 + j];
        float asc = oab[0], vsc = ovb[0];
#pragma unroll
        for (int j = 0; j < 20; ++j) {
            float oj = fmaxf(ord[j], 0.f);
            asc += oj * oaW[j];
            vsc += oj * ovW[j];
        }
        OS[(size_t)m * 48 + 32 + dd] = make_float2(asc, vsc);
    } else {
        __shared__ float sred[4][11];
        int t = threadIdx.x;
        int n = ((int)blockIdx.x - AB - DB) * 256 + t;
        float w = 0.f;
        float wv[10];
#pragma unroll
        for (int c = 0; c < 10; ++c) wv[c] = 0.f;
        if (n < N) {
            float v[20];
#pragma unroll
            for (int j = 0; j < 20; ++j) v[j] = vtb[j];
            {
                const float4* pc = (const float4*)(xc + n * PAD);
                float4 c0 = pc[0], c1 = pc[1], c2 = pc[2];
                float fv[10] = {c0.x, c0.y, c0.z, c0.w, c1.x, c1.y, c1.z, c1.w,
                                c2.x, c2.y};
#pragma unroll
                for (int k = 0; k < 10; ++k)
#pragma unroll
                    for (int j = 0; j < 20; ++j) v[j] += fv[k] * vtW[k * 20 + j];
            }
#pragma unroll
            for (int k = 0; k < 15; ++k) {
                float fv = x1[n * 15 + k];
#pragma unroll
                for (int j = 0; j < 20; ++j) v[j] += fv * vtW[(10 + k) * 20 + j];
            }
#pragma unroll
            for (int k = 0; k < 4; ++k) {
                float fv = x2[k];
#pragma unroll
                for (int j = 0; j < 20; ++j) v[j] += fv * vtW[(25 + k) * 20 + j];
            }
            float sc = vab[0];
#pragma unroll
            for (int j = 0; j < 20; ++j) {
                v[j] = fmaxf(v[j], 0.f);
                sc += v[j] * vaW[j];
            }
            w = __expf(sc);
#pragma unroll
            for (int c = 0; c < 10; ++c) {
                float t2 = vvb[c];
#pragma unroll
                for (int j = 0; j < 20; ++j) t2 += v[j] * vvW[j * 10 + c];
                wv[c] = w * t2;
            }
        }
#pragma unroll
        for (int off = 32; off > 0; off >>= 1) {
            w += __shfl_xor(w, off);
#pragma unroll
            for (int c = 0; c < 10; ++c) wv[c] += __shfl_xor(wv[c], off);
        }
        int wave = t >> 6, lane = t & 63;
        if (lane == 0) {
            sred[wave][0] = w;
#pragma unroll
            for (int c = 0; c < 10; ++c) sred[wave][1 + c] = wv[c];
        }
        __syncthreads();
        if (t == 0) {
#pragma unroll
            for (int c = 0; c < 11; ++c) {
                float s = sred[0][c] + sred[1][c] + sred[2][c] + sred[3][c];
                atomicAdd(&vsums[c], s);
            }
        }
    }
}

// Per-move softmax over 48 orders.
__global__ __launch_bounds__(256) void k_moves(
    const float2* __restrict__ OS, float* __restrict__ pm, int M)
{
    int m = blockIdx.x * 256 + threadIdx.x;
    if (m >= M) return;
    const float2* p = OS + (size_t)m * 48;
    float mx = -1e30f;
#pragma unroll
    for (int o = 0; o < 48; ++o) mx = fmaxf(mx, p[o].x);
    float Z = 0.f, num = 0.f;
#pragma unroll
    for (int o = 0; o < 48; ++o) {
        float e = __expf(p[o].x - mx);
        Z += e;
        num += e * p[o].y;
    }
    pm[m] = num / Z;
}

// out[1..M] = log_softmax(pm); thread 1023 computes V -> out[0].
__global__ __launch_bounds__(1024) void k_final(
    const float* __restrict__ pm, const float* __restrict__ vsums,
    const float* __restrict__ vlW, const float* __restrict__ vlb,
    float* __restrict__ out, int M)
{
    __shared__ float red[16];
    __shared__ float sval;
    int t = threadIdx.x;
    int wave = t >> 6, lane = t & 63;
    if (t == 1023) {
        float inv = 1.f / vsums[0];
        float V = vlb[0];
#pragma unroll
        for (int j = 0; j < 10; ++j) V += fmaxf(vsums[1 + j] * inv, 0.f) * vlW[j];
        out[0] = tanhf(V);
    }
    float mx = -1e30f;
    for (int i = t; i < M; i += 1024) mx = fmaxf(mx, pm[i]);
#pragma unroll
    for (int off = 32; off > 0; off >>= 1) mx = fmaxf(mx, __shfl_xor(mx, off));
    if (lane == 0) red[wave] = mx;
    __syncthreads();
    if (t == 0) {
        float m2 = red[0];
        for (int i = 1; i < 16; ++i) m2 = fmaxf(m2, red[i]);
        sval = m2;
    }
    __syncthreads();
    float smax = sval;
    float sum = 0.f;
    for (int i = t; i < M; i += 1024) sum += __expf(pm[i] - smax);
#pragma unroll
    for (int off = 32; off > 0; off >>= 1) sum += __shfl_xor(sum, off);
    if (lane == 0) red[wave] = sum;
    __syncthreads();
    if (t == 0) {
        float s2 = 0.f;
        for (int i = 0; i < 16; ++i) s2 += red[i];
        sval = s2;
    }
    __syncthreads();
    float lse = smax + logf(sval);
    for (int i = t; i < M; i += 1024) out[1 + i] = pm[i] - lse;
}

extern "C" void kernel_launch(void* const* d_in, const int* in_sizes, int n_in,
                              void* d_out, int out_size, void* d_ws, size_t ws_size,
                              hipStream_t stream)
{
    const float* x1   = (const float*)d_in[0];
    const float* x2   = (const float*)d_in[1];
    const int*   edges = (const int*)d_in[2];
    const int*   asrc = (const int*)d_in[3];
    const int*   adst = (const int*)d_in[4];
    const float* aarm = (const float*)d_in[5];
    const int*   dtgt = (const int*)d_in[6];
    const float* darm = (const float*)d_in[7];
    const float* initW = (const float*)d_in[8];
    const float* initb = (const float*)d_in[9];
    const float* g1Wl = (const float*)d_in[10];
    const float* g1Wr = (const float*)d_in[11];
    const float* g1att = (const float*)d_in[12];
    const float* g1b = (const float*)d_in[13];
    const float* g2Wl = (const float*)d_in[14];
    const float* g2Wr = (const float*)d_in[15];
    const float* g2att = (const float*)d_in[16];
    const float* g2b = (const float*)d_in[17];
    const float* g3Wl = (const float*)d_in[18];
    const float* g3Wr = (const float*)d_in[19];
    const float* g3att = (const float*)d_in[20];
    const float* g3b = (const float*)d_in[21];
    const float* vtW = (const float*)d_in[22];
    const float* vtb = (const float*)d_in[23];
    const float* vaW = (const float*)d_in[24];
    const float* vab = (const float*)d_in[25];
    const float* vvW = (const float*)d_in[26];
    const float* vvb = (const float*)d_in[27];
    const float* vlW = (const float*)d_in[28];
    const float* vlb = (const float*)d_in[29];
    const float* atW = (const float*)d_in[30];
    const float* atb = (const float*)d_in[31];
    const float* dtW = (const float*)d_in[32];
    const float* dtb = (const float*)d_in[33];
    const float* oaW = (const float*)d_in[34];
    const float* oab = (const float*)d_in[35];
    const float* ovW = (const float*)d_in[36];
    const float* ovb = (const float*)d_in[37];

    const int N = in_sizes[0] / 15;
    const int E = in_sizes[2] / 2;
    const int M = in_sizes[3] / 32;
    const int Etot = E + N;
    const int NBK = (N + 127) >> 7;
    const int PA = (E + CHK - 1) / CHK;
    const int TOT = NBK * PA;

    float* ws = (float*)d_ws;
    size_t off = 0;
    float* XU = ws + off; off += (size_t)N * PAD;
    float* XA = ws + off; off += (size_t)N * PAD;
    float* XB = ws + off; off += (size_t)N * PAD;
    float* XC = ws + off; off += (size_t)N * PAD;
    unsigned* XLb = (unsigned*)(ws + off); off += (size_t)N * LP;
    float* XR = ws + off; off += (size_t)N * PAD;
    int* sidx = (int*)(ws + off); off += Etot;
    unsigned* pairs = (unsigned*)(ws + off); off += E;
    int* deg = (int*)(ws + off); off += N;
    int* rowptr = (int*)(ws + off); off += N + 8;
    int* cntg = (int*)(ws + off); off += TOT + 8;
    int* bases = (int*)(ws + off); off += TOT + 8;
    int* bsumA = (int*)(ws + off); off += 1024;
    int* boffA = (int*)(ws + off); off += 1024;
    float* VS = ws + off; off += 16;
    float* PM = ws + off; off += M;
    float2* OS = (float2*)(ws + off); off += (size_t)M * 48 * 2;

    float* outp = (float*)d_out;

    const int NB = (N + 255) / 256;
    const int NG = (N + 15) / 16;
    const int AB = (M * 32 + 255) / 256;
    const int DB = (M * 16 + 255) / 256;
    const int SCA = (TOT + 1023) / 1024;  // <= 1024 for k_scanB
    const int* esrc = edges;
    const int* edst = edges + E;

    k_a1_init<<<PA + NB, 256, 0, stream>>>(edst, E, cntg, PA,
                                           x1, initW, initb, XU, N, NBK);
    k_scanA<<<SCA, 1024, 0, stream>>>(cntg, bases, bsumA, TOT);
    k_scanB<<<1, 1024, 0, stream>>>(bsumA, boffA, SCA, VS, rowptr, N, Etot);
    k_scanC<<<SCA, 1024, 0, stream>>>(bases, boffA, TOT);
    // A2 clustered placement || transform layer 1
    k_a2tr1<<<PA + NB, 256, 0, stream>>>(esrc, edst, E, bases, pairs, PA,
                                         XU, x1, g1Wl, g1Wr, XLb, XR, N, NBK);
    k_b<<<NBK, 256, 0, stream>>>(pairs, bases, rowptr, deg, sidx, N, NBK, PA, E);
    k_gather<<<NG, 256, 0, stream>>>(rowptr, deg, sidx, XLb, XR, g1att, g1b, XA, N);

    k_transform<2><<<NB, 256, 0, stream>>>(XA, XU, nullptr, x1, g2Wl, g2Wr, XLb, XR, N);
    k_gather<<<NG, 256, 0, stream>>>(rowptr, deg, sidx, XLb, XR, g2att, g2b, XB, N);

    k_transform<3><<<NB, 256, 0, stream>>>(XB, XA, XU, x1, g3Wl, g3Wr, XLb, XR, N);
    k_gather<<<NG, 256, 0, stream>>>(rowptr, deg, sidx, XLb, XR, g3att, g3b, XC, N);

    k_scores<<<AB + DB + NB, 256, 0, stream>>>(XC, x1, x2, asrc, adst, aarm,
                                               dtgt, darm, atW, atb, dtW, dtb,
                                               oaW, oab, ovW, ovb,
                                               vtW, vtb, vaW, vab, vvW, vvb,
                                               VS, OS, AB, DB, NB, N, M);
    k_moves<<<(M + 255) / 256, 256, 0, stream>>>(OS, PM, M);
    k_final<<<1, 1024, 0, stream>>>(PM, VS, vlW, vlb, outp, M);
}

// Round 10
// 399.648 us; speedup vs baseline: 1.0568x; 1.0568x over previous
//
#include <hip/hip_runtime.h>
#include <math.h>

// Model8 R10: revert to R7 CSR pipeline (exact-placement A2, best measured).
// New: packed policy-feature rows PF[n] = [xc(10), x1[1..14](14)] as 24 bf16
// in one 64B line, written by gather-3's epilogue. k_scores attack = 2 line
// touches (was ~4-5), deploy = 1; rows loaded upfront as 3x uint4 for MLP;
// __launch_bounds__(256,4) to avoid the VGPR=36 load serialization.

#define PAD 12    // padded row stride for fp32 [N,10] arrays (48B)
#define LP 8      // XLb packed row stride in u32 (32B)
#define PFP 16    // PFb packed row stride in u32 (64B, line-aligned)
#define MAXB 784  // LDS bucket array size (>= (N+127)/128)
#define CHK 8192  // edges per A1 chunk

__device__ __forceinline__ float lrelu02(float v) { return v > 0.f ? v : 0.2f * v; }

__device__ __forceinline__ unsigned pk_bf16(float a, float b)
{
    unsigned ua = __float_as_uint(a), ub = __float_as_uint(b);
    ua += 0x7fffu + ((ua >> 16) & 1u);
    ub += 0x7fffu + ((ub >> 16) & 1u);
    return (ua >> 16) | (ub & 0xffff0000u);
}
__device__ __forceinline__ float bf_lo(unsigned u) { return __uint_as_float(u << 16); }
__device__ __forceinline__ float bf_hi(unsigned u) { return __uint_as_float(u & 0xffff0000u); }

// Streaming transform body: accumulators only, uniform weight reads.
template <int NS>
__device__ __forceinline__ void transform_body(
    int n, const float* __restrict__ s0, const float* __restrict__ s1,
    const float* __restrict__ s2, const float* __restrict__ x1,
    const float* __restrict__ Wl, const float* __restrict__ Wr,
    unsigned* __restrict__ XLb, float* __restrict__ XR)
{
    float al[10], ar[10];
#pragma unroll
    for (int g = 0; g < 10; ++g) { al[g] = 0.f; ar[g] = 0.f; }
    int o = 0;
#define TB_BLOCK(SP)                                                        \
    {                                                                       \
        const float4* pr = (const float4*)((SP) + n * PAD);                 \
        float4 v0 = pr[0], v1 = pr[1], v2 = pr[2];                          \
        float fv[10] = {v0.x, v0.y, v0.z, v0.w, v1.x, v1.y, v1.z, v1.w,     \
                        v2.x, v2.y};                                        \
        _Pragma("unroll") for (int k = 0; k < 10; ++k)                      \
        {                                                                   \
            _Pragma("unroll") for (int g = 0; g < 10; ++g)                  \
            {                                                               \
                al[g] += fv[k] * Wl[(o + k) * 10 + g];                      \
                ar[g] += fv[k] * Wr[(o + k) * 10 + g];                      \
            }                                                               \
        }                                                                   \
        o += 10;                                                            \
    }
    if constexpr (NS >= 1) TB_BLOCK(s0)
    if constexpr (NS >= 2) TB_BLOCK(s1)
    if constexpr (NS >= 3) TB_BLOCK(s2)
#undef TB_BLOCK
#pragma unroll
    for (int k = 0; k < 15; ++k) {
        float fv = x1[n * 15 + k];
#pragma unroll
        for (int g = 0; g < 10; ++g) {
            al[g] += fv * Wl[(o + k) * 10 + g];
            ar[g] += fv * Wr[(o + k) * 10 + g];
        }
    }
    uint4 q0;
    q0.x = pk_bf16(al[0], al[1]);
    q0.y = pk_bf16(al[2], al[3]);
    q0.z = pk_bf16(al[4], al[5]);
    q0.w = pk_bf16(al[6], al[7]);
    uint4 q1;
    q1.x = pk_bf16(al[8], al[9]);
    q1.y = 0; q1.z = 0; q1.w = 0;
    uint4* pb = (uint4*)(XLb + (size_t)n * LP);
    pb[0] = q0;
    pb[1] = q1;
    float4* po = (float4*)(XR + n * PAD);
    po[0] = make_float4(ar[0], ar[1], ar[2], ar[3]);
    po[1] = make_float4(ar[4], ar[5], ar[6], ar[7]);
    po[2] = make_float4(ar[8], ar[9], 0.f, 0.f);
}

// Fused: blocks [0,PA) -> A1 (LDS hist -> pos[i] + cntg column);
// [PA,..) -> x_ = relu(x1@W+b).
__global__ __launch_bounds__(256) void k_a1_init(
    const int* __restrict__ edst, int E, unsigned short* __restrict__ pos,
    int* __restrict__ cntg, int PA,
    const float* __restrict__ x1, const float* __restrict__ W,
    const float* __restrict__ b, float* __restrict__ xo, int N, int NBK)
{
    if ((int)blockIdx.x < PA) {
        __shared__ int h[MAXB];
        for (int j = threadIdx.x; j < NBK; j += 256) h[j] = 0;
        __syncthreads();
        int base = blockIdx.x * CHK;
        for (int k = 0; k < CHK / 256; ++k) {
            int i = base + k * 256 + threadIdx.x;
            if (i < E) {
                int bkt = edst[i] >> 7;
                int p = atomicAdd(&h[bkt], 1);
                pos[i] = (unsigned short)p;
            }
        }
        __syncthreads();
        for (int j = threadIdx.x; j < NBK; j += 256)
            cntg[(size_t)j * PA + blockIdx.x] = h[j];
    } else {
        int n = ((int)blockIdx.x - PA) * 256 + (int)threadIdx.x;
        if (n >= N) return;
        float acc[10];
#pragma unroll
        for (int g = 0; g < 10; ++g) acc[g] = b[g];
#pragma unroll
        for (int k = 0; k < 15; ++k) {
            float fv = x1[n * 15 + k];
#pragma unroll
            for (int g = 0; g < 10; ++g) acc[g] += fv * W[k * 10 + g];
        }
        float4* po = (float4*)(xo + n * PAD);
        po[0] = make_float4(fmaxf(acc[0], 0.f), fmaxf(acc[1], 0.f),
                            fmaxf(acc[2], 0.f), fmaxf(acc[3], 0.f));
        po[1] = make_float4(fmaxf(acc[4], 0.f), fmaxf(acc[5], 0.f),
                            fmaxf(acc[6], 0.f), fmaxf(acc[7], 0.f));
        po[2] = make_float4(fmaxf(acc[8], 0.f), fmaxf(acc[9], 0.f), 0.f, 0.f);
    }
}

// Scan stage A.
__global__ __launch_bounds__(1024) void k_scanA(
    const int* __restrict__ cntg, int* __restrict__ bases,
    int* __restrict__ bsumA, int TOT)
{
    __shared__ int wsum[16];
    int t = threadIdx.x;
    int i = blockIdx.x * 1024 + t;
    int lane = t & 63, w = t >> 6;
    int x = (i < TOT) ? cntg[i] : 0;
    int incl = x;
#pragma unroll
    for (int off = 1; off < 64; off <<= 1) {
        int u = __shfl_up(incl, off);
        if (lane >= off) incl += u;
    }
    if (lane == 63) wsum[w] = incl;
    __syncthreads();
    int woff = 0;
    for (int k = 0; k < w; ++k) woff += wsum[k];
    incl += woff;
    if (i < TOT) bases[i] = incl - x;
    if (t == 1023) bsumA[blockIdx.x] = incl;
}

// Scan stage B (single block) + zero vsums + rowptr[N] = Etot.
__global__ __launch_bounds__(512) void k_scanB(
    const int* __restrict__ bsumA, int* __restrict__ boffA, int NBLKA,
    float* __restrict__ vsums, int* __restrict__ rowptr, int N, int Etot)
{
    __shared__ int wsum[8];
    int t = threadIdx.x;
    int lane = t & 63, w = t >> 6;
    int x = (t < NBLKA) ? bsumA[t] : 0;
    int incl = x;
#pragma unroll
    for (int off = 1; off < 64; off <<= 1) {
        int u = __shfl_up(incl, off);
        if (lane >= off) incl += u;
    }
    if (lane == 63) wsum[w] = incl;
    __syncthreads();
    int woff = 0;
    for (int k = 0; k < w; ++k) woff += wsum[k];
    incl += woff;
    if (t < NBLKA) boffA[t] = incl - x;
    if (t < 16) vsums[t] = 0.f;
    if (t == 0) rowptr[N] = Etot;
}

// Scan stage C.
__global__ __launch_bounds__(1024) void k_scanC(
    int* __restrict__ bases, const int* __restrict__ boffA, int TOT)
{
    int i = blockIdx.x * 1024 + threadIdx.x;
    if (i < TOT) bases[i] += boffA[blockIdx.x];
}

// A2: one fully parallel placement pass.
__global__ __launch_bounds__(256) void k_a2(
    const int* __restrict__ esrc, const int* __restrict__ edst, int E,
    const int* __restrict__ bases, const unsigned short* __restrict__ pos,
    unsigned* __restrict__ pairs, int PA)
{
    int i = blockIdx.x * 256 + threadIdx.x;
    if (i >= E) return;
    int d = edst[i], s = esrc[i];
    int bkt = d >> 7;
    int blk = i / CHK;
    int dest = bases[(size_t)bkt * PA + blk] + (int)pos[i];
    pairs[dest] = (unsigned)s | ((unsigned)(d & 127) << 17);
}

// Fused: blocks [0,NBK) -> per-bucket CSR build; [NBK,..) -> transform layer1.
__global__ __launch_bounds__(256) void k_b_tr1(
    const unsigned* __restrict__ pairs, const int* __restrict__ bases,
    int* __restrict__ rowptr, int* __restrict__ deg, int* __restrict__ sidx,
    int N, int NBK, int PA, int E,
    const float* __restrict__ s0a, const float* __restrict__ x1,
    const float* __restrict__ Wl, const float* __restrict__ Wr,
    unsigned* __restrict__ XLb, float* __restrict__ XR, int NB)
{
    if ((int)blockIdx.x < NBK) {
        __shared__ int cnt[128];
        __shared__ int cur[128];
        __shared__ int wtot;
        int t = threadIdx.x;
        if (t < 128) cnt[t] = 0;
        __syncthreads();
        int b = blockIdx.x;
        int p0 = bases[(size_t)b * PA];
        int p1 = (b + 1 < NBK) ? bases[(size_t)(b + 1) * PA] : E;
        int n0 = b << 7;
        int nn = N - n0; nn = nn < 0 ? 0 : (nn > 128 ? 128 : nn);
        for (int i = p0 + t; i < p1; i += 256) atomicAdd(&cnt[pairs[i] >> 17], 1);
        __syncthreads();
        int x = 0, incl = 0;
        if (t < 128) {
            x = cnt[t] + (t < nn ? 1 : 0);
            incl = x;
            int lane = t & 63;
#pragma unroll
            for (int off = 1; off < 64; off <<= 1) {
                int u = __shfl_up(incl, off);
                if (lane >= off) incl += u;
            }
            if (t == 63) wtot = incl;
        }
        __syncthreads();
        int sb = p0 + (b << 7);
        if (t < 128) {
            if (t >= 64) incl += wtot;
            int st = incl - x;
            if (t < nn) {
                int r = sb + st;
                rowptr[n0 + t] = r;
                deg[n0 + t] = cnt[t] + 1;
                sidx[r] = n0 + t;        // self-loop slot 0
                cur[t] = st + 1;
            } else {
                cur[t] = st;
            }
        }
        __syncthreads();
        for (int i = p0 + t; i < p1; i += 256) {
            unsigned w = pairs[i];
            int l = w >> 17, s = w & 0x1FFFF;
            int off = atomicAdd(&cur[l], 1);
            sidx[sb + off] = s;
        }
    } else {
        int n = ((int)blockIdx.x - NBK) * 256 + (int)threadIdx.x;
        if (n >= N) return;
        transform_body<1>(n, s0a, nullptr, nullptr, x1, Wl, Wr, XLb, XR);
    }
}

// Transform (layers 2/3).
template <int NS>
__global__ __launch_bounds__(256) void k_transform(
    const float* __restrict__ s0, const float* __restrict__ s1,
    const float* __restrict__ s2, const float* __restrict__ x1,
    const float* __restrict__ Wl, const float* __restrict__ Wr,
    unsigned* __restrict__ XLb, float* __restrict__ XR, int N)
{
    int n = blockIdx.x * blockDim.x + threadIdx.x;
    if (n >= N) return;
    transform_body<NS>(n, s0, s1, s2, x1, Wl, Wr, XLb, XR);
}

// CSR gather + edge softmax + finalize. 16 lanes/node, batch-2 ILP.
// If PFb != nullptr (layer 3): also emit packed policy-feature row
// PF[n] = [out(10), x1[n][1..14](14)] as 24 bf16 in one 64B line.
__global__ __launch_bounds__(256) void k_gather(
    const int* __restrict__ rowptr, const int* __restrict__ deg,
    const int* __restrict__ sidx,
    const unsigned* __restrict__ XLb, const float* __restrict__ XR,
    const float* __restrict__ att, const float* __restrict__ b,
    float* __restrict__ xo, unsigned* __restrict__ PFb,
    const float* __restrict__ x1, int N)
{
    int node = blockIdx.x * 16 + (threadIdx.x >> 4);
    int l16 = threadIdx.x & 15;
    float acc[10];
#pragma unroll
    for (int g = 0; g < 10; ++g) acc[g] = 0.f;
    float den = 0.f;
    float satt[10];
#pragma unroll
    for (int g = 0; g < 10; ++g) satt[g] = att[g];
    if (node < N) {
        const float4* pr = (const float4*)(XR + node * PAD);
        float4 r0 = pr[0], r1 = pr[1], r2 = pr[2];
        float xr[10] = {r0.x, r0.y, r0.z, r0.w, r1.x, r1.y, r1.z, r1.w, r2.x, r2.y};
        int start = rowptr[node];
        int dgr = deg[node];
        int j = l16;
        while (j + 16 < dgr) {
            int s0 = sidx[start + j];
            int s1 = sidx[start + j + 16];
            const unsigned* pl0 = XLb + (size_t)s0 * LP;
            const unsigned* pl1 = XLb + (size_t)s1 * LP;
            uint4 qa = *(const uint4*)pl0;
            unsigned qa4 = pl0[4];
            uint4 qb = *(const uint4*)pl1;
            unsigned qb4 = pl1[4];
            float xa[10] = {bf_lo(qa.x), bf_hi(qa.x), bf_lo(qa.y), bf_hi(qa.y),
                            bf_lo(qa.z), bf_hi(qa.z), bf_lo(qa.w), bf_hi(qa.w),
                            bf_lo(qa4), bf_hi(qa4)};
            float xb[10] = {bf_lo(qb.x), bf_hi(qb.x), bf_lo(qb.y), bf_hi(qb.y),
                            bf_lo(qb.z), bf_hi(qb.z), bf_lo(qb.w), bf_hi(qb.w),
                            bf_lo(qb4), bf_hi(qb4)};
            float ea = 0.f, eb = 0.f;
#pragma unroll
            for (int g = 0; g < 10; ++g) {
                ea += lrelu02(xa[g] + xr[g]) * satt[g];
                eb += lrelu02(xb[g] + xr[g]) * satt[g];
            }
            float exa = __expf(ea), exb = __expf(eb);
#pragma unroll
            for (int g = 0; g < 10; ++g) acc[g] += exa * xa[g] + exb * xb[g];
            den += exa + exb;
            j += 32;
        }
        if (j < dgr) {
            int s = sidx[start + j];
            const unsigned* pl = XLb + (size_t)s * LP;
            uint4 q = *(const uint4*)pl;
            unsigned q4 = pl[4];
            float xl[10] = {bf_lo(q.x), bf_hi(q.x), bf_lo(q.y), bf_hi(q.y),
                            bf_lo(q.z), bf_hi(q.z), bf_lo(q.w), bf_hi(q.w),
                            bf_lo(q4), bf_hi(q4)};
            float e = 0.f;
#pragma unroll
            for (int g = 0; g < 10; ++g) e += lrelu02(xl[g] + xr[g]) * satt[g];
            float ex = __expf(e);
#pragma unroll
            for (int g = 0; g < 10; ++g) acc[g] += ex * xl[g];
            den += ex;
        }
    }
#pragma unroll
    for (int off = 1; off < 16; off <<= 1) {
        den += __shfl_xor(den, off);
#pragma unroll
        for (int g = 0; g < 10; ++g) acc[g] += __shfl_xor(acc[g], off);
    }
    if (node < N && l16 == 0) {
        float inv = 1.f / den;
        float r[10];
#pragma unroll
        for (int g = 0; g < 10; ++g) r[g] = fmaxf(acc[g] * inv + b[g], 0.f);
        float4* po = (float4*)(xo + node * PAD);
        po[0] = make_float4(r[0], r[1], r[2], r[3]);
        po[1] = make_float4(r[4], r[5], r[6], r[7]);
        po[2] = make_float4(r[8], r[9], 0.f, 0.f);
        if (PFb) {
            float xf[14];
#pragma unroll
            for (int k = 0; k < 14; ++k) xf[k] = x1[node * 15 + 1 + k];
            uint4 q0, q1, q2;
            q0.x = pk_bf16(r[0], r[1]);
            q0.y = pk_bf16(r[2], r[3]);
            q0.z = pk_bf16(r[4], r[5]);
            q0.w = pk_bf16(r[6], r[7]);
            q1.x = pk_bf16(r[8], r[9]);
            q1.y = pk_bf16(xf[0], xf[1]);
            q1.z = pk_bf16(xf[2], xf[3]);
            q1.w = pk_bf16(xf[4], xf[5]);
            q2.x = pk_bf16(xf[6], xf[7]);
            q2.y = pk_bf16(xf[8], xf[9]);
            q2.z = pk_bf16(xf[10], xf[11]);
            q2.w = pk_bf16(xf[12], xf[13]);
            uint4* qp = (uint4*)(PFb + (size_t)node * PFP);
            qp[0] = q0;
            qp[1] = q1;
            qp[2] = q2;
        }
    }
}

// Fused homogeneous scoring on packed PF rows:
//   blocks [0,AB)            thread-per-attack-order -> OS[m*48 + a]
//   blocks [AB,AB+DB)        thread-per-deploy-order -> OS[m*48 + 32 + dd]
//   blocks [AB+DB,AB+DB+NB)  value-head accumulation -> vsums
// PF[n][0..9] = xc[n], PF[n][10+j] = x1[n][1+j] (j=0..13), bf16.
__global__ __launch_bounds__(256, 4) void k_scores(
    const unsigned* __restrict__ PFb, const float* __restrict__ xc,
    const float* __restrict__ x1, const float* __restrict__ x2,
    const int* __restrict__ asrc, const int* __restrict__ adst,
    const float* __restrict__ aarm,
    const int* __restrict__ dtgt, const float* __restrict__ darm,
    const float* __restrict__ atW, const float* __restrict__ atb,
    const float* __restrict__ dtW, const float* __restrict__ dtb,
    const float* __restrict__ oaW, const float* __restrict__ oab,
    const float* __restrict__ ovW, const float* __restrict__ ovb,
    const float* __restrict__ vtW, const float* __restrict__ vtb,
    const float* __restrict__ vaW, const float* __restrict__ vab,
    const float* __restrict__ vvW, const float* __restrict__ vvb,
    float* __restrict__ vsums, float2* __restrict__ OS,
    int AB, int DB, int NB, int N, int M)
{
    if ((int)blockIdx.x < AB) {
        int i = blockIdx.x * 256 + threadIdx.x;
        if (i >= M * 32) return;
        int m = i >> 5, a = i & 31;
        int s = asrc[i], d = adst[i];
        float arm = aarm[i];
        // upfront loads: 2 lines, 6 uint4 in flight
        const uint4* ps = (const uint4*)(PFb + (size_t)s * PFP);
        const uint4* pd = (const uint4*)(PFb + (size_t)d * PFP);
        uint4 sA = ps[0], sB = ps[1], sC = ps[2];
        uint4 dA = pd[0], dB = pd[1], dC = pd[2];
        float fs[24] = {bf_lo(sA.x), bf_hi(sA.x), bf_lo(sA.y), bf_hi(sA.y),
                        bf_lo(sA.z), bf_hi(sA.z), bf_lo(sA.w), bf_hi(sA.w),
                        bf_lo(sB.x), bf_hi(sB.x), bf_lo(sB.y), bf_hi(sB.y),
                        bf_lo(sB.z), bf_hi(sB.z), bf_lo(sB.w), bf_hi(sB.w),
                        bf_lo(sC.x), bf_hi(sC.x), bf_lo(sC.y), bf_hi(sC.y),
                        bf_lo(sC.z), bf_hi(sC.z), bf_lo(sC.w), bf_hi(sC.w)};
        float fd[24] = {bf_lo(dA.x), bf_hi(dA.x), bf_lo(dA.y), bf_hi(dA.y),
                        bf_lo(dA.z), bf_hi(dA.z), bf_lo(dA.w), bf_hi(dA.w),
                        bf_lo(dB.x), bf_hi(dB.x), bf_lo(dB.y), bf_hi(dB.y),
                        bf_lo(dB.z), bf_hi(dB.z), bf_lo(dB.w), bf_hi(dB.w),
                        bf_lo(dC.x), bf_hi(dC.x), bf_lo(dC.y), bf_hi(dC.y),
                        bf_lo(dC.z), bf_hi(dC.z), bf_lo(dC.w), bf_hi(dC.w)};
        float ord[20];
#pragma unroll
        for (int j = 0; j < 20; ++j) ord[j] = atb[j];
        // rows 0-9: xc[s]
#pragma unroll
        for (int k = 0; k < 10; ++k)
#pragma unroll
            for (int j = 0; j < 20; ++j) ord[j] += fs[k] * atW[k * 20 + j];
        // rows 10-19: xc[d]
#pragma unroll
        for (int k = 0; k < 10; ++k)
#pragma unroll
            for (int j = 0; j < 20; ++j) ord[j] += fd[k] * atW[(10 + k) * 20 + j];
        // rows 20-31: x1[s][3..14] = fs[12..23]
#pragma unroll
        for (int k = 0; k < 12; ++k)
#pragma unroll
            for (int j = 0; j < 20; ++j)
                ord[j] += fs[12 + k] * atW[(20 + k) * 20 + j];
        // rows 32-45: x1[d][1..14] = fd[10..23]
#pragma unroll
        for (int k = 0; k < 14; ++k)
#pragma unroll
            for (int j = 0; j < 20; ++j)
                ord[j] += fd[10 + k] * atW[(32 + k) * 20 + j];
        float extra = 0.6f * arm - 0.7f * (fd[12] + fd[13]);
#pragma unroll
        for (int j = 0; j < 20; ++j)
            ord[j] += arm * atW[46 * 20 + j] + extra * atW[47 * 20 + j];
        float asc = oab[0], vsc = ovb[0];
#pragma unroll
        for (int j = 0; j < 20; ++j) {
            float oj = fmaxf(ord[j], 0.f);
            asc += oj * oaW[j];
            vsc += oj * ovW[j];
        }
        OS[(size_t)m * 48 + a] = make_float2(asc, vsc);
    } else if ((int)blockIdx.x < AB + DB) {
        int i = ((int)blockIdx.x - AB) * 256 + threadIdx.x;
        if (i >= M * 16) return;
        int m = i >> 4, dd = i & 15;
        int tg = dtgt[i];
        float arm = darm[i];
        const uint4* pt = (const uint4*)(PFb + (size_t)tg * PFP);
        uint4 tA = pt[0], tB = pt[1], tC = pt[2];
        float ft[24] = {bf_lo(tA.x), bf_hi(tA.x), bf_lo(tA.y), bf_hi(tA.y),
                        bf_lo(tA.z), bf_hi(tA.z), bf_lo(tA.w), bf_hi(tA.w),
                        bf_lo(tB.x), bf_hi(tB.x), bf_lo(tB.y), bf_hi(tB.y),
                        bf_lo(tB.z), bf_hi(tB.z), bf_lo(tB.w), bf_hi(tB.w),
                        bf_lo(tC.x), bf_hi(tC.x), bf_lo(tC.y), bf_hi(tC.y),
                        bf_lo(tC.z), bf_hi(tC.z), bf_lo(tC.w), bf_hi(tC.w)};
        float ord[20];
#pragma unroll
        for (int j = 0; j < 20; ++j) ord[j] = dtb[j];
        // rows 0-9: xc[tg]
#pragma unroll
        for (int k = 0; k < 10; ++k)
#pragma unroll
            for (int j = 0; j < 20; ++j) ord[j] += ft[k] * dtW[k * 20 + j];
        // rows 10-21: x1[tg][3..14] = ft[12..23]
#pragma unroll
        for (int k = 0; k < 12; ++k)
#pragma unroll
            for (int j = 0; j < 20; ++j)
                ord[j] += ft[12 + k] * dtW[(10 + k) * 20 + j];
#pragma unroll
        for (int j = 0; j < 20; ++j) ord[j] += arm * dtW[22 * 20 + j];
        float asc = oab[0], vsc = ovb[0];
#pragma unroll
        for (int j = 0; j < 20; ++j) {
            float oj = fmaxf(ord[j], 0.f);
            asc += oj * oaW[j];
            vsc += oj * ovW[j];
        }
        OS[(size_t)m * 48 + 32 + dd] = make_float2(asc, vsc);
    } else {
        __shared__ float sred[4][11];
        int t = threadIdx.x;
        int n = ((int)blockIdx.x - AB - DB) * 256 + t;
        float w = 0.f;
        float wv[10];
#pragma unroll
        for (int c = 0; c < 10; ++c) wv[c] = 0.f;
        if (n < N) {
            float v[20];
#pragma unroll
            for (int j = 0; j < 20; ++j) v[j] = vtb[j];
            {
                const float4* pc = (const float4*)(xc + n * PAD);
                float4 c0 = pc[0], c1 = pc[1], c2 = pc[2];
                float fv[10] = {c0.x, c0.y, c0.z, c0.w, c1.x, c1.y, c1.z, c1.w,
                                c2.x, c2.y};
#pragma unroll
                for (int k = 0; k < 10; ++k)
#pragma unroll
                    for (int j = 0; j < 20; ++j) v[j] += fv[k] * vtW[k * 20 + j];
            }
#pragma unroll
            for (int k = 0; k < 15; ++k) {
                float fv = x1[n * 15 + k];
#pragma unroll
                for (int j = 0; j < 20; ++j) v[j] += fv * vtW[(10 + k) * 20 + j];
            }
#pragma unroll
            for (int k = 0; k < 4; ++k) {
                float fv = x2[k];
#pragma unroll
                for (int j = 0; j < 20; ++j) v[j] += fv * vtW[(25 + k) * 20 + j];
            }
            float sc = vab[0];
#pragma unroll
            for (int j = 0; j < 20; ++j) {
                v[j] = fmaxf(v[j], 0.f);
                sc += v[j] * vaW[j];
            }
            w = __expf(sc);
#pragma unroll
            for (int c = 0; c < 10; ++c) {
                float t2 = vvb[c];
#pragma unroll
                for (int j = 0; j < 20; ++j) t2 += v[j] * vvW[j * 10 + c];
                wv[c] = w * t2;
            }
        }
#pragma unroll
        for (int off = 32; off > 0; off >>= 1) {
            w += __shfl_xor(w, off);
#pragma unroll
            for (int c = 0; c < 10; ++c) wv[c] += __shfl_xor(wv[c], off);
        }
        int wave = t >> 6, lane = t & 63;
        if (lane == 0) {
            sred[wave][0] = w;
#pragma unroll
            for (int c = 0; c < 10; ++c) sred[wave][1 + c] = wv[c];
        }
        __syncthreads();
        if (t == 0) {
#pragma unroll
            for (int c = 0; c < 11; ++c) {
                float s = sred[0][c] + sred[1][c] + sred[2][c] + sred[3][c];
                atomicAdd(&vsums[c], s);
            }
        }
    }
}

// Per-move softmax over 48 orders.
__global__ __launch_bounds__(256) void k_moves(
    const float2* __restrict__ OS, float* __restrict__ pm, int M)
{
    int m = blockIdx.x * 256 + threadIdx.x;
    if (m >= M) return;
    const float2* p = OS + (size_t)m * 48;
    float mx = -1e30f;
#pragma unroll
    for (int o = 0; o < 48; ++o) mx = fmaxf(mx, p[o].x);
    float Z = 0.f, num = 0.f;
#pragma unroll
    for (int o = 0; o < 48; ++o) {
        float e = __expf(p[o].x - mx);
        Z += e;
        num += e * p[o].y;
    }
    pm[m] = num / Z;
}

// out[1..M] = log_softmax(pm); thread 1023 computes V -> out[0].
__global__ __launch_bounds__(1024) void k_final(
    const float* __restrict__ pm, const float* __restrict__ vsums,
    const float* __restrict__ vlW, const float* __restrict__ vlb,
    float* __restrict__ out, int M)
{
    __shared__ float red[16];
    __shared__ float sval;
    int t = threadIdx.x;
    int wave = t >> 6, lane = t & 63;
    if (t == 1023) {
        float inv = 1.f / vsums[0];
        float V = vlb[0];
#pragma unroll
        for (int j = 0; j < 10; ++j) V += fmaxf(vsums[1 + j] * inv, 0.f) * vlW[j];
        out[0] = tanhf(V);
    }
    float mx = -1e30f;
    for (int i = t; i < M; i += 1024) mx = fmaxf(mx, pm[i]);
#pragma unroll
    for (int off = 32; off > 0; off >>= 1) mx = fmaxf(mx, __shfl_xor(mx, off));
    if (lane == 0) red[wave] = mx;
    __syncthreads();
    if (t == 0) {
        float m2 = red[0];
        for (int i = 1; i < 16; ++i) m2 = fmaxf(m2, red[i]);
        sval = m2;
    }
    __syncthreads();
    float smax = sval;
    float sum = 0.f;
    for (int i = t; i < M; i += 1024) sum += __expf(pm[i] - smax);
#pragma unroll
    for (int off = 32; off > 0; off >>= 1) sum += __shfl_xor(sum, off);
    if (lane == 0) red[wave] = sum;
    __syncthreads();
    if (t == 0) {
        float s2 = 0.f;
        for (int i = 0; i < 16; ++i) s2 += red[i];
        sval = s2;
    }
    __syncthreads();
    float lse = smax + logf(sval);
    for (int i = t; i < M; i += 1024) out[1 + i] = pm[i] - lse;
}

extern "C" void kernel_launch(void* const* d_in, const int* in_sizes, int n_in,
                              void* d_out, int out_size, void* d_ws, size_t ws_size,
                              hipStream_t stream)
{
    const float* x1   = (const float*)d_in[0];
    const float* x2   = (const float*)d_in[1];
    const int*   edges = (const int*)d_in[2];
    const int*   asrc = (const int*)d_in[3];
    const int*   adst = (const int*)d_in[4];
    const float* aarm = (const float*)d_in[5];
    const int*   dtgt = (const int*)d_in[6];
    const float* darm = (const float*)d_in[7];
    const float* initW = (const float*)d_in[8];
    const float* initb = (const float*)d_in[9];
    const float* g1Wl = (const float*)d_in[10];
    const float* g1Wr = (const float*)d_in[11];
    const float* g1att = (const float*)d_in[12];
    const float* g1b = (const float*)d_in[13];
    const float* g2Wl = (const float*)d_in[14];
    const float* g2Wr = (const float*)d_in[15];
    const float* g2att = (const float*)d_in[16];
    const float* g2b = (const float*)d_in[17];
    const float* g3Wl = (const float*)d_in[18];
    const float* g3Wr = (const float*)d_in[19];
    const float* g3att = (const float*)d_in[20];
    const float* g3b = (const float*)d_in[21];
    const float* vtW = (const float*)d_in[22];
    const float* vtb = (const float*)d_in[23];
    const float* vaW = (const float*)d_in[24];
    const float* vab = (const float*)d_in[25];
    const float* vvW = (const float*)d_in[26];
    const float* vvb = (const float*)d_in[27];
    const float* vlW = (const float*)d_in[28];
    const float* vlb = (const float*)d_in[29];
    const float* atW = (const float*)d_in[30];
    const float* atb = (const float*)d_in[31];
    const float* dtW = (const float*)d_in[32];
    const float* dtb = (const float*)d_in[33];
    const float* oaW = (const float*)d_in[34];
    const float* oab = (const float*)d_in[35];
    const float* ovW = (const float*)d_in[36];
    const float* ovb = (const float*)d_in[37];

    const int N = in_sizes[0] / 15;
    const int E = in_sizes[2] / 2;
    const int M = in_sizes[3] / 32;
    const int Etot = E + N;
    const int NBK = (N + 127) >> 7;
    const int PA = (E + CHK - 1) / CHK;
    const int TOT = NBK * PA;

    float* ws = (float*)d_ws;
    size_t off = 0;
    float* XU = ws + off; off += (size_t)N * PAD;
    float* XA = ws + off; off += (size_t)N * PAD;
    float* XB = ws + off; off += (size_t)N * PAD;
    float* XC = ws + off; off += (size_t)N * PAD;
    unsigned* XLb = (unsigned*)(ws + off); off += (size_t)N * LP;
    float* XR = ws + off; off += (size_t)N * PAD;
    unsigned* PFb = (unsigned*)(ws + off); off += (size_t)N * PFP;  // 64B-aligned
    int* sidx = (int*)(ws + off); off += Etot;
    unsigned* pairs = (unsigned*)(ws + off); off += E;
    int* deg = (int*)(ws + off); off += N;
    int* rowptr = (int*)(ws + off); off += N + 8;
    int* cntg = (int*)(ws + off); off += TOT + 8;
    int* bases = (int*)(ws + off); off += TOT + 8;
    int* bsumA = (int*)(ws + off); off += 512;
    int* boffA = (int*)(ws + off); off += 512;
    float* VS = ws + off; off += 16;
    float* PM = ws + off; off += M;
    float2* OS = (float2*)(ws + off); off += (size_t)M * 48 * 2;
    // pos (u16, E entries = 6.4MB) overlays XA..XB (9.6MB); dead before gather1.
    unsigned short* pos = (unsigned short*)XA;

    float* outp = (float*)d_out;

    const int NB = (N + 255) / 256;
    const int NG = (N + 15) / 16;
    const int AB = (M * 32 + 255) / 256;
    const int DB = (M * 16 + 255) / 256;
    const int SCA = (TOT + 1023) / 1024;  // <= 512 for k_scanB
    const int* esrc = edges;
    const int* edst = edges + E;

    k_a1_init<<<PA + NB, 256, 0, stream>>>(edst, E, pos, cntg, PA,
                                           x1, initW, initb, XU, N, NBK);
    k_scanA<<<SCA, 1024, 0, stream>>>(cntg, bases, bsumA, TOT);
    k_scanB<<<1, 512, 0, stream>>>(bsumA, boffA, SCA, VS, rowptr, N, Etot);
    k_scanC<<<SCA, 1024, 0, stream>>>(bases, boffA, TOT);
    k_a2<<<(E + 255) / 256, 256, 0, stream>>>(esrc, edst, E, bases, pos, pairs, PA);
    k_b_tr1<<<NBK + NB, 256, 0, stream>>>(pairs, bases, rowptr, deg, sidx, N, NBK, PA, E,
                                          XU, x1, g1Wl, g1Wr, XLb, XR, NB);
    k_gather<<<NG, 256, 0, stream>>>(rowptr, deg, sidx, XLb, XR, g1att, g1b,
                                     XA, nullptr, x1, N);

    k_transform<2><<<NB, 256, 0, stream>>>(XA, XU, nullptr, x1, g2Wl, g2Wr, XLb, XR, N);
    k_gather<<<NG, 256, 0, stream>>>(rowptr, deg, sidx, XLb, XR, g2att, g2b,
                                     XB, nullptr, x1, N);

    k_transform<3><<<NB, 256, 0, stream>>>(XB, XA, XU, x1, g3Wl, g3Wr, XLb, XR, N);
    k_gather<<<NG, 256, 0, stream>>>(rowptr, deg, sidx, XLb, XR, g3att, g3b,
                                     XC, PFb, x1, N);

    k_scores<<<AB + DB + NB, 256, 0, stream>>>(PFb, XC, x1, x2, asrc, adst, aarm,
                                               dtgt, darm, atW, atb, dtW, dtb,
                                               oaW, oab, ovW, ovb,
                                               vtW, vtb, vaW, vab, vvW, vvb,
                                               VS, OS, AB, DB, NB, N, M);
    k_moves<<<(M + 255) / 256, 256, 0, stream>>>(OS, PM, M);
    k_final<<<1, 1024, 0, stream>>>(PM, VS, vlW, vlb, outp, M);
}